// Round 5
// baseline (463.308 us; speedup 1.0000x reference)
//
#include <hip/hip_runtime.h>

#define N_NODES 100000
#define D_FEAT  128
#define N_EDGES 625000

#define NBLK  256        // == CU count; 1 block/CU forced via 88 KB LDS
#define NTHR  1024
#define NPB   391        // nodes per bucket; 256*391 = 100096 >= 100000
#define CAP   3072       // packed slots per bucket (avg 2441, sd ~49 -> 12 sigma)
#define CHUNK 2442       // 256*2442 = 625152 >= 625000

typedef float vfloat4 __attribute__((ext_vector_type(4)));

#define MAGIC(k) (0x5EED0C00 + (k))

// Flag-array grid barrier: slot [k][b] written only by block b with a per-k magic.
// Poisoned ws (0xAAAAAAAA) != magic, so no init pass is needed.
__device__ __forceinline__ void grid_barrier(int* flags, int k) {
    __syncthreads();
    if (threadIdx.x == 0) {
        __threadfence();  // release my block's prior global writes (L2 writeback)
        __hip_atomic_store(&flags[k * NBLK + blockIdx.x], MAGIC(k),
                           __ATOMIC_RELEASE, __HIP_MEMORY_SCOPE_AGENT);
    }
    if (threadIdx.x < NBLK) {
        while (__hip_atomic_load(&flags[k * NBLK + threadIdx.x],
                                 __ATOMIC_ACQUIRE, __HIP_MEMORY_SCOPE_AGENT) != MAGIC(k)) {
            __builtin_amdgcn_s_sleep(1);
        }
    }
    __syncthreads();
    __threadfence();  // drop stale L1/L2 lines before reading others' data
}

__global__ __launch_bounds__(NTHR) void fused_kernel(
    const int* __restrict__ recv, const int* __restrict__ src,
    const vfloat4* __restrict__ ds_in4, const vfloat4* __restrict__ ds_out4,
    vfloat4* __restrict__ out4,
    int* __restrict__ counts,   // [bucket][chunk] 256x256
    int* __restrict__ packed,   // 256 * CAP
    int* __restrict__ flags)    // 3 * NBLK
{
    __shared__ int smem[22528];  // 88 KB -> exactly 1 block/CU -> 256 blocks co-resident
    const int t = threadIdx.x;
    const int b = blockIdx.x;

    // defense-in-depth vs stale flags if ws re-poison were ever skipped
    if (t < 3)
        __hip_atomic_store(&flags[t * NBLK + b], 0, __ATOMIC_RELAXED, __HIP_MEMORY_SCOPE_AGENT);

    // ---- Phase A: per-chunk histogram over 256 node-buckets (LDS atomics) ----
    int* hist = smem;  // 256
    if (t < 256) hist[t] = 0;
    __syncthreads();
    const int cbeg = b * CHUNK;
    const int cend = min(cbeg + CHUNK, N_EDGES);
    for (int i = cbeg + t; i < cend; i += NTHR)
        atomicAdd(&hist[recv[i] / NPB], 1);
    __syncthreads();
    if (t < 256) counts[t * NBLK + b] = hist[t];   // counts[bucket][chunk=b]

    grid_barrier(flags, 0);

    // ---- Phase B: block b = bucket b; exclusive scan over its 256 chunk counts ----
    int* tmp = smem;  // 256
    int v = 0;
    if (t < 256) { v = counts[b * NBLK + t]; tmp[t] = v; }
    __syncthreads();
    for (int off = 1; off < 256; off <<= 1) {
        int x = 0;
        if (t < 256 && t >= off) x = tmp[t - off];
        __syncthreads();
        if (t < 256) tmp[t] += x;
        __syncthreads();
    }
    if (t < 256) counts[b * NBLK + t] = tmp[t] - v;  // exclusive
    if (t == 255) smem[22000] = tmp[255];            // bucket total (persists in LDS)

    grid_barrier(flags, 1);

    // ---- Phase C: block b = chunk b; scatter packed edges into bucket regions ----
    int* cur = smem;  // 256 (does not touch smem[22000])
    if (t < 256) cur[t] = t * CAP + counts[t * NBLK + b];
    __syncthreads();
    for (int i = cbeg + t; i < cend; i += NTHR) {
        int r  = recv[i];
        int s  = src[i];
        int bk = r / NPB;
        int pos = atomicAdd(&cur[bk], 1);          // LDS atomic
        packed[pos] = ((r - bk * NPB) << 17) | s;  // local (9b) | src (17b)
    }

    grid_barrier(flags, 2);

    // ---- Phase D: block b = bucket b; in-LDS counting sort to per-node CSR ----
    const int cnt = smem[22000];
    int* cnt_lds = smem;            // 512
    int* excl    = smem + 512;      // 512
    int* cursor  = smem + 1024;     // 512
    int* pk_lds  = smem + 2048;         // CAP
    int* ssrc_l  = smem + 2048 + CAP;   // CAP
    if (t < 512) cnt_lds[t] = 0;
    __syncthreads();
    for (int i = t; i < cnt; i += NTHR) {
        int pk = packed[b * CAP + i];
        pk_lds[i] = pk;
        atomicAdd(&cnt_lds[pk >> 17], 1);
    }
    __syncthreads();
    int v2 = 0;
    if (t < 512) { v2 = cnt_lds[t]; excl[t] = v2; }
    __syncthreads();
    for (int off = 1; off < 512; off <<= 1) {
        int x = 0;
        if (t < 512 && t >= off) x = excl[t - off];
        __syncthreads();
        if (t < 512) excl[t] += x;
        __syncthreads();
    }
    if (t < 512) { excl[t] -= v2; cursor[t] = excl[t]; }
    __syncthreads();
    for (int i = t; i < cnt; i += NTHR) {
        int pk = pk_lds[i];
        int slot = atomicAdd(&cursor[pk >> 17], 1);  // LDS atomic
        ssrc_l[slot] = pk & 0x1FFFF;
    }
    __syncthreads();

    // ---- Phase E: gather own bucket; 32 lanes/node, float4/lane ----
    const int g = t >> 5, lane = t & 31;  // 32 groups of 32 lanes
    for (int ln = g; ln < NPB; ln += 32) {
        int node = b * NPB + ln;
        if (node >= N_NODES) break;
        int beg = excl[ln];
        int d   = cnt_lds[ln];
        vfloat4 acc = __builtin_nontemporal_load(&ds_out4[node * 32 + lane]);
        for (int k = 0; k < d; k++) {
            int s = ssrc_l[beg + k];               // LDS broadcast per group
            acc += ds_in4[s * 32 + lane];          // 512 B coalesced row segment
        }
        float inv = 1.0f / (1.0f + (float)d);
        acc *= inv;
        __builtin_nontemporal_store(acc, &out4[node * 32 + lane]);
    }
}

extern "C" void kernel_launch(void* const* d_in, const int* in_sizes, int n_in,
                              void* d_out, int out_size, void* d_ws, size_t ws_size,
                              hipStream_t stream) {
    const float* ds_in  = (const float*)d_in[0];
    const float* ds_out = (const float*)d_in[1];
    const int*   eidx   = (const int*)d_in[2];   // [2, N_EDGES] row-major int32
    const int* recv = eidx;
    const int* src  = eidx + N_EDGES;
    float* out = (float*)d_out;

    int* counts = (int*)d_ws;                 // 256*256
    int* packed = counts + NBLK * NBLK;       // 256*CAP
    int* flags  = packed + NBLK * CAP;        // 3*NBLK

    fused_kernel<<<NBLK, NTHR, 0, stream>>>(
        recv, src, (const vfloat4*)ds_in, (const vfloat4*)ds_out, (vfloat4*)out,
        counts, packed, flags);
}